// Round 1
// 173.943 us; speedup vs baseline: 1.2423x; 1.2423x over previous
//
#include <hip/hip_runtime.h>
#include <hip/hip_bf16.h>

#define N_NODES 100000
#define E_TOTAL 800000
#define E1      400000    // first min(4,k_max)*N edges -> scale-1 (subset of scale-2)
#define D       64
#define CAP     32        // max degree slots; P(deg>32 | Poisson(8)) ~ 2e-11/node

// ---- bucketed CSR build ----------------------------------------------------
#define NPB        256                            // nodes per bucket
#define NB         ((N_NODES + NPB - 1) / NPB)    // 391 buckets
#define BSTRIDE    (NPB * CAP)                    // 8192 u32: records alias entries span
#define BCAP       3072                           // mean 2048, sigma~45 -> 22 sigma margin
#define EPB        4096                           // edges per bucket-pass block
#define NBKT_BLKS  ((E_TOTAL + EPB - 1) / EPB)    // 196

typedef short s16x8 __attribute__((ext_vector_type(8)));   // 8 bf16 bit patterns
typedef float f32x4 __attribute__((ext_vector_type(4)));
typedef unsigned u32x4 __attribute__((ext_vector_type(4)));

// ws layout (u32 units):
//   cnt[N] | entries[N*CAP] | W1b[2048] | W2b[2048] | Wgb[4096] | bias[192] | cur[400] | Xb[N*32]
#define WS_CNT     0
#define WS_ENTRIES (N_NODES)                        // byte 400000, 16-B aligned
#define WS_W1B     (WS_ENTRIES + N_NODES * CAP)
#define WS_W2B     (WS_W1B + 2048)
#define WS_WGB     (WS_W2B + 2048)
#define WS_BIAS    (WS_WGB + 4096)                  // b1[64] | b2[64] | bg[64] fp32
#define WS_CUR     (WS_BIAS + 192)                  // NB bucket cursors (+pad to 400)
#define WS_XB      (WS_CUR + 400)                   // 16-B aligned
#define WS_NEED_BYTES ((size_t)(WS_XB + (size_t)N_NODES * D / 2) * 4)   // ~26 MB

// conv gid ranges (after the NBKT_BLKS bucket blocks)
#define R_X   (N_NODES * D / 8)      // 800000 threads: x convert, 8 elems/thread
#define R_W   (R_X + 2048)           // weights: 8 elems/thread (16384)
#define R_B   (R_W + 24)             // biases: 8 elems/thread (192)
#define CONV_BLOCKS ((R_B + 255) / 256)

__device__ __forceinline__ float ldv(const void* p, size_t idx, int fp32)
{
    return fp32 ? ((const float*)p)[idx]
                : __bfloat162float(((const __hip_bfloat16*)p)[idx]);
}

// block-local dtype detection (blockDim.x == 256).
__device__ __forceinline__ void detect2(const int* ei, const unsigned short* xu,
                                        int* s2, int& e64, int& fp32)
{
    if (threadIdx.x == 0) { s2[0] = 0; s2[1] = 0; }
    __syncthreads();
    if (threadIdx.x < 16 && ei[2 * threadIdx.x + 1] != 0) atomicOr(&s2[0], 1);
    { unsigned u = xu[threadIdx.x]; if (((u >> 7) & 0xFF) >= 0x90) atomicOr(&s2[1], 1); }
    __syncthreads();
    e64 = (s2[0] == 0); fp32 = s2[1];
}

// ---------------------------------------------------------------------------
// prep: bucket blocks (first NBKT_BLKS) bin edges into coarse buckets with
// LDS-aggregated cursors (77K global atomics instead of 800K, ~40-B write
// runs instead of random 4-B scatter). Remaining blocks: x->bf16 Xb,
// weights->bf16, biases->f32. Records alias the entries region (bucket b's
// records live inside bucket b's own entries span; csr_kernel reads them
// before overwriting).
// ---------------------------------------------------------------------------
__global__ __launch_bounds__(256) void prep_kernel(
    const void* __restrict__ xv, const int* __restrict__ ei,
    const void* __restrict__ W1v, const void* __restrict__ b1v,
    const void* __restrict__ W2v, const void* __restrict__ b2v,
    const void* __restrict__ Wgv, const void* __restrict__ bgv,
    unsigned* __restrict__ ws, int use_xb)
{
    __shared__ int s2[2];
    __shared__ unsigned hist[NB];
    __shared__ unsigned bbase[NB];
    int e64, fp32;
    detect2(ei, (const unsigned short*)xv, s2, e64, fp32);

    if (blockIdx.x < NBKT_BLKS) {                 // ---- bucket pass ----
        for (int j = threadIdx.x; j < NB; j += 256) hist[j] = 0;
        __syncthreads();

        const int e0 = blockIdx.x * EPB;
        unsigned recv[16], br[16];
#pragma unroll
        for (int i = 0; i < 16; ++i) {
            const int e = e0 + i * 256 + threadIdx.x;
            br[i] = 0xFFFFFFFFu;
            if (e < E_TOTAL) {
                int src, tgt;
                if (e64) {
                    src = (int)((const uint2*)ei)[e].x;
                    tgt = (int)((const uint2*)ei)[E_TOTAL + e].x;
                } else {
                    src = ei[e]; tgt = ei[E_TOTAL + e];
                }
                const unsigned b = (unsigned)src >> 8;       // bucket
                const unsigned r = atomicAdd(&hist[b], 1u);  // LDS rank
                recv[i] = (unsigned)tgt
                        | ((e < E1) ? (1u << 17) : 0u)
                        | (((unsigned)src & (NPB - 1)) << 18);
                br[i] = (b << 16) | r;                       // r <= 4095
            }
        }
        __syncthreads();
        for (int j = threadIdx.x; j < NB; j += 256) {
            const unsigned h = hist[j];
            bbase[j] = h ? atomicAdd(ws + WS_CUR + j, h) : 0u;
        }
        __syncthreads();
#pragma unroll
        for (int i = 0; i < 16; ++i) {
            if (br[i] != 0xFFFFFFFFu) {
                const unsigned b = br[i] >> 16, r = br[i] & 0xFFFFu;
                const unsigned pos = bbase[b] + r;
                if (pos < BCAP)
                    ws[WS_ENTRIES + (size_t)b * BSTRIDE + pos] = recv[i];
            }
        }
        return;
    }

    // ---- conversion blocks ----
    const int gid = (blockIdx.x - NBKT_BLKS) * 256 + threadIdx.x;
    __hip_bfloat16* Xb  = (__hip_bfloat16*)(ws + WS_XB);
    __hip_bfloat16* W1b = (__hip_bfloat16*)(ws + WS_W1B);
    __hip_bfloat16* W2b = (__hip_bfloat16*)(ws + WS_W2B);
    __hip_bfloat16* Wgb = (__hip_bfloat16*)(ws + WS_WGB);
    float* bias = (float*)(ws + WS_BIAS);

    if (gid < R_X) {                          // x -> Xb: 8 elems/thread
        if (use_xb && fp32) {
            const f32x4 v0 = ((const f32x4*)xv)[2 * gid];
            const f32x4 v1 = ((const f32x4*)xv)[2 * gid + 1];
            s16x8 o;
#pragma unroll
            for (int j = 0; j < 4; ++j) {
                o[j]     = (short)__bfloat16_as_ushort(__float2bfloat16(v0[j]));
                o[4 + j] = (short)__bfloat16_as_ushort(__float2bfloat16(v1[j]));
            }
            *(s16x8*)(Xb + (size_t)gid * 8) = o;
        }
    } else if (gid < R_W) {                   // weights: 16384 elems
        const int j = gid - R_X;
#pragma unroll
        for (int k = 0; k < 8; ++k) {
            const int i = j * 8 + k;
            if (i < 4096)       W1b[i]        = __float2bfloat16(ldv(W1v, i, fp32));
            else if (i < 8192)  W2b[i - 4096] = __float2bfloat16(ldv(W2v, i - 4096, fp32));
            else                Wgb[i - 8192] = __float2bfloat16(ldv(Wgv, i - 8192, fp32));
        }
    } else if (gid < R_B) {                   // biases: 192 elems
        const int j = gid - R_W;
#pragma unroll
        for (int k = 0; k < 8; ++k) {
            const int i = j * 8 + k;
            if (i < 64)       bias[i] = ldv(b1v, i, fp32);
            else if (i < 128) bias[i] = ldv(b2v, i - 64, fp32);
            else              bias[i] = ldv(bgv, i - 128, fp32);
        }
    }
}

// ---------------------------------------------------------------------------
// csr_kernel: one block per bucket. Reads the bucket's packed records, bins
// per-node in LDS (LDS atomics), then writes cnt[] and entries[] for its 256
// contiguous nodes fully coalesced (overwrites the record span it just read).
// Output format identical to the old atomic CSR fill.
// ---------------------------------------------------------------------------
__global__ __launch_bounds__(256) void csr_kernel(unsigned* __restrict__ ws)
{
    __shared__ unsigned cnt_l[NPB];
    __shared__ __align__(16) unsigned ent[NPB * CAP];   // 32 KB

    const int b  = blockIdx.x;
    const int n0 = b * NPB;
    const int nn = min(NPB, N_NODES - n0);

    cnt_l[threadIdx.x] = 0;
    __syncthreads();

    const unsigned C = min(ws[WS_CUR + b], (unsigned)BCAP);
    for (unsigned r = threadIdx.x; r < C; r += 256) {
        const unsigned rec = ws[WS_ENTRIES + (size_t)b * BSTRIDE + r];
        const unsigned sl  = rec >> 18;
        const unsigned p   = atomicAdd(&cnt_l[sl], 1u);
        if (p < CAP)
            ent[sl * CAP + p] = (rec & 0x1FFFFu) | ((rec & (1u << 17)) ? 0x80000000u : 0u);
    }
    __syncthreads();

    // coalesced entries write: nn*CAP u32 (unused slots carry garbage; fused
    // only ever reads lane < deg slots)
    const int tot4 = (nn * CAP) / 4;
    u32x4* dst = (u32x4*)(ws + WS_ENTRIES + (size_t)n0 * CAP);
    const u32x4* srcp = (const u32x4*)ent;
    for (int j = threadIdx.x; j < tot4; j += 256) dst[j] = srcp[j];

    if (threadIdx.x < nn) ws[WS_CNT + n0 + threadIdx.x] = cnt_l[threadIdx.x];
}

// ---------------------------------------------------------------------------
// fused gather + MFMA epilogue. 256 thr = 4 waves = 16 nodes/block.
// (unchanged from previous round)
// ---------------------------------------------------------------------------
__global__ __launch_bounds__(256) void fused_kernel(
    const unsigned* __restrict__ ws, const void* __restrict__ xv,
    void* __restrict__ outv, int use_xb)
{
    __shared__ __align__(16) __hip_bfloat16 sS[16][136];  // s1|s2 rows per node
    __shared__ __align__(16) __hip_bfloat16 sO[16][136];  // o1|o2 rows per node
    __shared__ int s2d[2];

    if (threadIdx.x == 0) s2d[0] = 0;
    __syncthreads();
    { unsigned u = ((const unsigned short*)xv)[threadIdx.x];
      if (((u >> 7) & 0xFF) >= 0x90) atomicOr(&s2d[0], 1); }
    __syncthreads();
    const int fp32 = s2d[0];

    const int w    = threadIdx.x >> 6;
    const int lane = threadIdx.x & 63;
    const int base = blockIdx.x * 16;

    const int direct_f32 = (fp32 && !use_xb);     // fallback: no Xb space
    const char* xb = (use_xb && fp32) ? (const char*)(ws + WS_XB) : (const char*)xv;
    const float* xf = (const float*)xv;

    // ---- phase A: prefetch entry rows + degree for this wave's 4 nodes ----
    unsigned entv[4]; int degc[4]; unsigned degr[4];
#pragma unroll
    for (int i = 0; i < 4; ++i) {
        const int n = base + w * 4 + i;
        degr[i] = ws[WS_CNT + n];
        degc[i] = (int)min(degr[i], (unsigned)CAP);
        entv[i] = (lane < degc[i]) ? ws[WS_ENTRIES + (size_t)n * CAP + lane] : 0u;
    }

    const int half = lane >> 5;       // which of the 2 rows in a chunk
    const int cc   = lane & 31;       // dim-pair index: dims 2cc, 2cc+1

#pragma unroll
    for (int i = 0; i < 4; ++i) {
        const int nl = w * 4 + i;
        const int c1 = (int)__popcll(__ballot(entv[i] & 0x80000000u));

        float s1x = 0.f, s1y = 0.f, s2x = 0.f, s2y = 0.f;

        if (!direct_f32) {
            const int chunks = (degc[i] + 1) >> 1;
#pragma unroll 4
            for (int r = 0; r < chunks; ++r) {
                const int j = 2 * r + half;
                const unsigned en = __shfl(entv[i], j);       // ds_bpermute
                if (j < degc[i]) {
                    const size_t tgt = (size_t)(en & 0x7FFFFFFFu);
                    const unsigned u = *(const unsigned*)(xb + (tgt << 7) + (cc << 2));
                    const float fx = __uint_as_float(u << 16);          // dim 2cc
                    const float fy = __uint_as_float(u & 0xFFFF0000u);  // dim 2cc+1
                    const float fl = (en & 0x80000000u) ? 1.f : 0.f;
                    s2x += fx; s2y += fy;
                    s1x = fmaf(fl, fx, s1x); s1y = fmaf(fl, fy, s1y);
                }
            }
        } else {
            for (int j = 0; j < degc[i]; ++j) {
                const unsigned en = __builtin_amdgcn_readlane(entv[i], j);
                const float v = xf[(size_t)(en & 0x7FFFFFFFu) * D + lane];
                s2x += v;
                if (en & 0x80000000u) s1x += v;
            }
        }

        if (!direct_f32) {
            s1x += __shfl_xor(s1x, 32); s1y += __shfl_xor(s1y, 32);
            s2x += __shfl_xor(s2x, 32); s2y += __shfl_xor(s2y, 32);

            const float inv1 = 1.0f / ((float)c1 + 1e-6f);
            const float inv2 = 1.0f / ((float)degr[i] + 1e-6f);
            if (lane < 32) {
                const __hip_bfloat162 p1 = __float22bfloat162_rn({s1x * inv1, s1y * inv1});
                const __hip_bfloat162 p2 = __float22bfloat162_rn({s2x * inv2, s2y * inv2});
                *(__hip_bfloat162*)&sS[nl][2 * cc]      = p1;
                *(__hip_bfloat162*)&sS[nl][64 + 2 * cc] = p2;
            }
        } else {
            const float inv1 = 1.0f / ((float)c1 + 1e-6f);
            const float inv2 = 1.0f / ((float)degr[i] + 1e-6f);
            sS[nl][lane]      = __float2bfloat16(s1x * inv1);
            sS[nl][64 + lane] = __float2bfloat16(s2x * inv2);
        }
    }
    __syncthreads();

    // ---- phase B: MFMA epilogue; wave w computes output dims [16w,16w+16) ----
    const int m = lane & 15;          // A-row carrier / C-col index
    const int q = lane >> 4;          // quad
    const int nd = w * 16 + m;        // output dim this lane computes

    const s16x8* W1b = (const s16x8*)(ws + WS_W1B);
    const s16x8* W2b = (const s16x8*)(ws + WS_W2B);
    const s16x8* Wgb = (const s16x8*)(ws + WS_WGB);
    const float* bias = (const float*)(ws + WS_BIAS);

    const s16x8 a1c0 = *(const s16x8*)&sS[m][q * 8];
    const s16x8 a1c1 = *(const s16x8*)&sS[m][32 + q * 8];
    const s16x8 a2c0 = *(const s16x8*)&sS[m][64 + q * 8];
    const s16x8 a2c1 = *(const s16x8*)&sS[m][96 + q * 8];

    f32x4 z = {0.f, 0.f, 0.f, 0.f};
    z = __builtin_amdgcn_mfma_f32_16x16x32_bf16(a1c0, W1b[nd * 8 + q],     z, 0, 0, 0);
    z = __builtin_amdgcn_mfma_f32_16x16x32_bf16(a1c1, W1b[nd * 8 + 4 + q], z, 0, 0, 0);
    f32x4 y = {0.f, 0.f, 0.f, 0.f};
    y = __builtin_amdgcn_mfma_f32_16x16x32_bf16(a2c0, W2b[nd * 8 + q],     y, 0, 0, 0);
    y = __builtin_amdgcn_mfma_f32_16x16x32_bf16(a2c1, W2b[nd * 8 + 4 + q], y, 0, 0, 0);
    const float bb1 = bias[nd], bb2 = bias[64 + nd];
#pragma unroll
    for (int r = 0; r < 4; ++r) { z[r] += bb1; y[r] += bb2; }

#pragma unroll
    for (int r = 0; r < 4; ++r) {
        sO[q * 4 + r][nd]      = __float2bfloat16(z[r]);
        sO[q * 4 + r][64 + nd] = __float2bfloat16(y[r]);
    }
    __syncthreads();

    s16x8 ga[4];
#pragma unroll
    for (int c = 0; c < 4; ++c)
        ga[c] = *(const s16x8*)&sO[m][c * 32 + q * 8];

    f32x4 g4 = {0.f, 0.f, 0.f, 0.f};
#pragma unroll
    for (int c = 0; c < 4; ++c)
        g4 = __builtin_amdgcn_mfma_f32_16x16x32_bf16(ga[c], Wgb[nd * 16 + c * 4 + q], g4, 0, 0, 0);
    const float bbg = bias[128 + nd];

#pragma unroll
    for (int r = 0; r < 4; ++r) {
        const float g = 1.0f / (1.0f + __expf(-(g4[r] + bbg)));
        const float v = g * z[r] + (1.0f - g) * y[r];
        const size_t node = (size_t)(base + q * 4 + r);
        if (fp32) ((float*)outv)[node * 64 + nd] = v;
        else      ((__hip_bfloat16*)outv)[node * 64 + nd] = __float2bfloat16(v);
    }
}

// ---------------------------------------------------------------------------
extern "C" void kernel_launch(void* const* d_in, const int* in_sizes, int n_in,
                              void* d_out, int out_size, void* d_ws, size_t ws_size,
                              hipStream_t stream)
{
    const void* x  = d_in[0];
    const int*  ei = (const int*)d_in[1];
    unsigned* ws = (unsigned*)d_ws;

    const int use_xb = (ws_size >= WS_NEED_BYTES) ? 1 : 0;   // constant per dataset

    hipMemsetAsync(ws + WS_CUR, 0, NB * sizeof(unsigned), stream);
    prep_kernel<<<NBKT_BLKS + CONV_BLOCKS, 256, 0, stream>>>(
        x, ei, d_in[2], d_in[3], d_in[4], d_in[5], d_in[6], d_in[7], ws, use_xb);
    csr_kernel<<<NB, 256, 0, stream>>>(ws);
    fused_kernel<<<N_NODES / 16, 256, 0, stream>>>(ws, x, d_out, use_xb);
}

// Round 2
// 171.627 us; speedup vs baseline: 1.2591x; 1.0135x over previous
//
#include <hip/hip_runtime.h>
#include <hip/hip_bf16.h>

#define N_NODES 100000
#define E_TOTAL 800000
#define E1      400000    // first min(4,k_max)*N edges -> scale-1 (subset of scale-2)
#define D       64
#define CAP     32        // max degree slots; P(deg>32 | Poisson(8)) ~ 2e-11/node

// ---- bucketed CSR build ----------------------------------------------------
#define NPB        256                            // nodes per bucket
#define NB         ((N_NODES + NPB - 1) / NPB)    // 391 buckets
#define BSTRIDE    (NPB * CAP)                    // 8192 u32: records alias entries span
#define BCAP       3072                           // mean 2048, sigma~45 -> 22 sigma margin
#define EPB        4096                           // edges per bucket-pass block
#define NBKT_BLKS  ((E_TOTAL + EPB - 1) / EPB)    // 196

typedef short s16x8 __attribute__((ext_vector_type(8)));   // 8 bf16 bit patterns
typedef float f32x4 __attribute__((ext_vector_type(4)));
typedef unsigned u32x4 __attribute__((ext_vector_type(4)));

// ws layout (u32 units):
//   cnt[N] | entries[N*CAP] | W1b[2048] | W2b[2048] | Wgb[4096] | bias[192] | cur[400] | Xb[N*32]
#define WS_CNT     0
#define WS_ENTRIES (N_NODES)                        // byte 400000, 16-B aligned
#define WS_W1B     (WS_ENTRIES + N_NODES * CAP)
#define WS_W2B     (WS_W1B + 2048)
#define WS_WGB     (WS_W2B + 2048)
#define WS_BIAS    (WS_WGB + 4096)                  // b1[64] | b2[64] | bg[64] fp32
#define WS_CUR     (WS_BIAS + 192)                  // NB bucket cursors (+pad to 400)
#define WS_XB      (WS_CUR + 400)                   // 16-B aligned
#define WS_NEED_BYTES ((size_t)(WS_XB + (size_t)N_NODES * D / 2) * 4)   // ~26 MB

// conv gid ranges (after the NBKT_BLKS bucket blocks)
#define R_X   (N_NODES * D / 8)      // 800000 threads: x convert, 8 elems/thread
#define R_W   (R_X + 2048)           // weights: 8 elems/thread (16384)
#define R_B   (R_W + 24)             // biases: 8 elems/thread (192)
#define CONV_BLOCKS ((R_B + 255) / 256)

__device__ __forceinline__ float ldv(const void* p, size_t idx, int fp32)
{
    return fp32 ? ((const float*)p)[idx]
                : __bfloat162float(((const __hip_bfloat16*)p)[idx]);
}

// block-local dtype detection (blockDim.x == 256).
__device__ __forceinline__ void detect2(const int* ei, const unsigned short* xu,
                                        int* s2, int& e64, int& fp32)
{
    if (threadIdx.x == 0) { s2[0] = 0; s2[1] = 0; }
    __syncthreads();
    if (threadIdx.x < 16 && ei[2 * threadIdx.x + 1] != 0) atomicOr(&s2[0], 1);
    { unsigned u = xu[threadIdx.x]; if (((u >> 7) & 0xFF) >= 0x90) atomicOr(&s2[1], 1); }
    __syncthreads();
    e64 = (s2[0] == 0); fp32 = s2[1];
}

// ---------------------------------------------------------------------------
// prep: bucket blocks (first NBKT_BLKS) bin edges into coarse buckets with
// LDS-aggregated cursors. Edge loads hoisted ahead of the LDS-atomic loop so
// all 16 global loads are in flight before the dependent atomic chain starts.
// Remaining blocks: x->bf16 Xb, weights->bf16, biases->f32.
// ---------------------------------------------------------------------------
__global__ __launch_bounds__(256) void prep_kernel(
    const void* __restrict__ xv, const int* __restrict__ ei,
    const void* __restrict__ W1v, const void* __restrict__ b1v,
    const void* __restrict__ W2v, const void* __restrict__ b2v,
    const void* __restrict__ Wgv, const void* __restrict__ bgv,
    unsigned* __restrict__ ws, int use_xb)
{
    __shared__ int s2[2];
    __shared__ unsigned hist[NB];
    __shared__ unsigned bbase[NB];
    int e64, fp32;
    detect2(ei, (const unsigned short*)xv, s2, e64, fp32);

    if (blockIdx.x < NBKT_BLKS) {                 // ---- bucket pass ----
        for (int j = threadIdx.x; j < NB; j += 256) hist[j] = 0;
        __syncthreads();

        const int e0 = blockIdx.x * EPB;
        int srcv[16], tgtv[16];
#pragma unroll
        for (int i = 0; i < 16; ++i) {            // phase 1: all loads in flight
            const int e = e0 + i * 256 + threadIdx.x;
            srcv[i] = -1;
            if (e < E_TOTAL) {
                if (e64) {
                    srcv[i] = (int)((const uint2*)ei)[e].x;
                    tgtv[i] = (int)((const uint2*)ei)[E_TOTAL + e].x;
                } else {
                    srcv[i] = ei[e]; tgtv[i] = ei[E_TOTAL + e];
                }
            }
        }
        unsigned recv[16], br[16];
#pragma unroll
        for (int i = 0; i < 16; ++i) {            // phase 2: LDS rank
            const int e = e0 + i * 256 + threadIdx.x;
            br[i] = 0xFFFFFFFFu;
            if (srcv[i] >= 0) {
                const unsigned b = (unsigned)srcv[i] >> 8;   // bucket
                const unsigned r = atomicAdd(&hist[b], 1u);  // LDS rank
                recv[i] = (unsigned)tgtv[i]
                        | ((e < E1) ? (1u << 17) : 0u)
                        | (((unsigned)srcv[i] & (NPB - 1)) << 18);
                br[i] = (b << 16) | r;                       // r <= 4095
            }
        }
        __syncthreads();
        for (int j = threadIdx.x; j < NB; j += 256) {
            const unsigned h = hist[j];
            bbase[j] = h ? atomicAdd(ws + WS_CUR + j, h) : 0u;
        }
        __syncthreads();
#pragma unroll
        for (int i = 0; i < 16; ++i) {
            if (br[i] != 0xFFFFFFFFu) {
                const unsigned b = br[i] >> 16, r = br[i] & 0xFFFFu;
                const unsigned pos = bbase[b] + r;
                if (pos < BCAP)
                    ws[WS_ENTRIES + (size_t)b * BSTRIDE + pos] = recv[i];
            }
        }
        return;
    }

    // ---- conversion blocks ----
    const int gid = (blockIdx.x - NBKT_BLKS) * 256 + threadIdx.x;
    __hip_bfloat16* Xb  = (__hip_bfloat16*)(ws + WS_XB);
    __hip_bfloat16* W1b = (__hip_bfloat16*)(ws + WS_W1B);
    __hip_bfloat16* W2b = (__hip_bfloat16*)(ws + WS_W2B);
    __hip_bfloat16* Wgb = (__hip_bfloat16*)(ws + WS_WGB);
    float* bias = (float*)(ws + WS_BIAS);

    if (gid < R_X) {                          // x -> Xb: 8 elems/thread
        if (use_xb && fp32) {
            const f32x4 v0 = ((const f32x4*)xv)[2 * gid];
            const f32x4 v1 = ((const f32x4*)xv)[2 * gid + 1];
            s16x8 o;
#pragma unroll
            for (int j = 0; j < 4; ++j) {
                o[j]     = (short)__bfloat16_as_ushort(__float2bfloat16(v0[j]));
                o[4 + j] = (short)__bfloat16_as_ushort(__float2bfloat16(v1[j]));
            }
            *(s16x8*)(Xb + (size_t)gid * 8) = o;
        }
    } else if (gid < R_W) {                   // weights: 16384 elems
        const int j = gid - R_X;
#pragma unroll
        for (int k = 0; k < 8; ++k) {
            const int i = j * 8 + k;
            if (i < 4096)       W1b[i]        = __float2bfloat16(ldv(W1v, i, fp32));
            else if (i < 8192)  W2b[i - 4096] = __float2bfloat16(ldv(W2v, i - 4096, fp32));
            else                Wgb[i - 8192] = __float2bfloat16(ldv(Wgv, i - 8192, fp32));
        }
    } else if (gid < R_B) {                   // biases: 192 elems
        const int j = gid - R_W;
#pragma unroll
        for (int k = 0; k < 8; ++k) {
            const int i = j * 8 + k;
            if (i < 64)       bias[i] = ldv(b1v, i, fp32);
            else if (i < 128) bias[i] = ldv(b2v, i - 64, fp32);
            else              bias[i] = ldv(bgv, i - 128, fp32);
        }
    }
}

// ---------------------------------------------------------------------------
// csr_kernel: one block per bucket. Reads the bucket's packed records, bins
// per-node in LDS (LDS atomics), then writes cnt[] and entries[] for its 256
// contiguous nodes fully coalesced.
// ---------------------------------------------------------------------------
__global__ __launch_bounds__(256) void csr_kernel(unsigned* __restrict__ ws)
{
    __shared__ unsigned cnt_l[NPB];
    __shared__ __align__(16) unsigned ent[NPB * CAP];   // 32 KB

    const int b  = blockIdx.x;
    const int n0 = b * NPB;
    const int nn = min(NPB, N_NODES - n0);

    cnt_l[threadIdx.x] = 0;
    __syncthreads();

    const unsigned C = min(ws[WS_CUR + b], (unsigned)BCAP);
    for (unsigned r = threadIdx.x; r < C; r += 256) {
        const unsigned rec = ws[WS_ENTRIES + (size_t)b * BSTRIDE + r];
        const unsigned sl  = rec >> 18;
        const unsigned p   = atomicAdd(&cnt_l[sl], 1u);
        if (p < CAP)
            ent[sl * CAP + p] = (rec & 0x1FFFFu) | ((rec & (1u << 17)) ? 0x80000000u : 0u);
    }
    __syncthreads();

    const int tot4 = (nn * CAP) / 4;
    u32x4* dst = (u32x4*)(ws + WS_ENTRIES + (size_t)n0 * CAP);
    const u32x4* srcp = (const u32x4*)ent;
    for (int j = threadIdx.x; j < tot4; j += 256) dst[j] = srcp[j];

    if (threadIdx.x < nn) ws[WS_CNT + n0 + threadIdx.x] = cnt_l[threadIdx.x];
}

// ---------------------------------------------------------------------------
// fused gather + MFMA epilogue. 256 thr = 4 waves = 16 nodes/block.
// Gather rework (this round): the 4 nodes' chunk loops are INTERLEAVED into
// one loop (r-major, nodes unrolled inside, r unrolled x2) -> up to 8
// independent gather loads in flight per wave and no per-node serialization.
// Phase-A cnt/entries loads issued concurrently (entries masked after cnt
// arrives). Per-node summation order identical to previous round.
// ---------------------------------------------------------------------------
__global__ __launch_bounds__(256) void fused_kernel(
    const unsigned* __restrict__ ws, const void* __restrict__ xv,
    void* __restrict__ outv, int use_xb)
{
    __shared__ __align__(16) __hip_bfloat16 sS[16][136];  // s1|s2 rows per node
    __shared__ __align__(16) __hip_bfloat16 sO[16][136];  // o1|o2 rows per node
    __shared__ int s2d[2];

    if (threadIdx.x == 0) s2d[0] = 0;
    __syncthreads();
    { unsigned u = ((const unsigned short*)xv)[threadIdx.x];
      if (((u >> 7) & 0xFF) >= 0x90) atomicOr(&s2d[0], 1); }
    __syncthreads();
    const int fp32 = s2d[0];

    const int w    = threadIdx.x >> 6;
    const int lane = threadIdx.x & 63;
    const int base = blockIdx.x * 16;

    const int direct_f32 = (fp32 && !use_xb);     // fallback: no Xb space
    const char* xb = (use_xb && fp32) ? (const char*)(ws + WS_XB) : (const char*)xv;
    const float* xf = (const float*)xv;

    // ---- phase A: concurrent cnt + entry loads for this wave's 4 nodes ----
    unsigned eraw[4], entv[4], degr[4]; int degc[4];
#pragma unroll
    for (int i = 0; i < 4; ++i) {
        const int n = base + w * 4 + i;
        degr[i] = ws[WS_CNT + n];                                  // independent
        eraw[i] = (lane < CAP) ? ws[WS_ENTRIES + (size_t)n * CAP + lane] : 0u;
    }
#pragma unroll
    for (int i = 0; i < 4; ++i) {
        degc[i] = (int)min(degr[i], (unsigned)CAP);
        entv[i] = (lane < degc[i]) ? eraw[i] : 0u;                 // mask garbage
    }

    const int half = lane >> 5;       // which of the 2 rows in a chunk
    const int cc   = lane & 31;       // dim-pair index: dims 2cc, 2cc+1

    if (!direct_f32) {
        int c1[4];
#pragma unroll
        for (int i = 0; i < 4; ++i)
            c1[i] = (int)__popcll(__ballot(entv[i] & 0x80000000u));

        float s1x[4], s1y[4], s2x[4], s2y[4];
#pragma unroll
        for (int i = 0; i < 4; ++i) { s1x[i] = s1y[i] = s2x[i] = s2y[i] = 0.f; }

        int rmax = 0;
#pragma unroll
        for (int i = 0; i < 4; ++i) rmax = max(rmax, (degc[i] + 1) >> 1);

#pragma unroll 2
        for (int r = 0; r < rmax; ++r) {
#pragma unroll
            for (int i = 0; i < 4; ++i) {
                const int j = 2 * r + half;
                const unsigned en = __shfl(entv[i], j);       // ds_bpermute
                if (j < degc[i]) {
                    const unsigned off = ((en & 0x7FFFFFFFu) << 7) + ((unsigned)cc << 2);
                    const unsigned u = *(const unsigned*)(xb + off);
                    const float fx = __uint_as_float(u << 16);          // dim 2cc
                    const float fy = __uint_as_float(u & 0xFFFF0000u);  // dim 2cc+1
                    const float fl = (en & 0x80000000u) ? 1.f : 0.f;
                    s2x[i] += fx; s2y[i] += fy;
                    s1x[i] = fmaf(fl, fx, s1x[i]); s1y[i] = fmaf(fl, fy, s1y[i]);
                }
            }
        }

#pragma unroll
        for (int i = 0; i < 4; ++i) {
            const int nl = w * 4 + i;
            float a = s1x[i], b = s1y[i], c = s2x[i], d = s2y[i];
            a += __shfl_xor(a, 32); b += __shfl_xor(b, 32);
            c += __shfl_xor(c, 32); d += __shfl_xor(d, 32);
            const float inv1 = 1.0f / ((float)c1[i] + 1e-6f);
            const float inv2 = 1.0f / ((float)degr[i] + 1e-6f);
            if (lane < 32) {   // lanes 0..31 own dim pairs 0..31
                const __hip_bfloat162 p1 = __float22bfloat162_rn({a * inv1, b * inv1});
                const __hip_bfloat162 p2 = __float22bfloat162_rn({c * inv2, d * inv2});
                *(__hip_bfloat162*)&sS[nl][2 * cc]      = p1;
                *(__hip_bfloat162*)&sS[nl][64 + 2 * cc] = p2;
            }
        }
    } else {
        // fallback: direct fp32 x, scalar per-edge row loads (rare path)
#pragma unroll
        for (int i = 0; i < 4; ++i) {
            const int nl = w * 4 + i;
            const int c1 = (int)__popcll(__ballot(entv[i] & 0x80000000u));
            float s1x = 0.f, s2x = 0.f;
            for (int j = 0; j < degc[i]; ++j) {
                const unsigned en = __builtin_amdgcn_readlane(entv[i], j);
                const float v = xf[(size_t)(en & 0x7FFFFFFFu) * D + lane];
                s2x += v;
                if (en & 0x80000000u) s1x += v;
            }
            const float inv1 = 1.0f / ((float)c1 + 1e-6f);
            const float inv2 = 1.0f / ((float)degr[i] + 1e-6f);
            sS[nl][lane]      = __float2bfloat16(s1x * inv1);
            sS[nl][64 + lane] = __float2bfloat16(s2x * inv2);
        }
    }
    __syncthreads();

    // ---- phase B: MFMA epilogue; wave w computes output dims [16w,16w+16) ----
    const int m = lane & 15;          // A-row carrier / C-col index
    const int q = lane >> 4;          // quad
    const int nd = w * 16 + m;        // output dim this lane computes

    const s16x8* W1b = (const s16x8*)(ws + WS_W1B);
    const s16x8* W2b = (const s16x8*)(ws + WS_W2B);
    const s16x8* Wgb = (const s16x8*)(ws + WS_WGB);
    const float* bias = (const float*)(ws + WS_BIAS);

    const s16x8 a1c0 = *(const s16x8*)&sS[m][q * 8];
    const s16x8 a1c1 = *(const s16x8*)&sS[m][32 + q * 8];
    const s16x8 a2c0 = *(const s16x8*)&sS[m][64 + q * 8];
    const s16x8 a2c1 = *(const s16x8*)&sS[m][96 + q * 8];

    f32x4 z = {0.f, 0.f, 0.f, 0.f};
    z = __builtin_amdgcn_mfma_f32_16x16x32_bf16(a1c0, W1b[nd * 8 + q],     z, 0, 0, 0);
    z = __builtin_amdgcn_mfma_f32_16x16x32_bf16(a1c1, W1b[nd * 8 + 4 + q], z, 0, 0, 0);
    f32x4 y = {0.f, 0.f, 0.f, 0.f};
    y = __builtin_amdgcn_mfma_f32_16x16x32_bf16(a2c0, W2b[nd * 8 + q],     y, 0, 0, 0);
    y = __builtin_amdgcn_mfma_f32_16x16x32_bf16(a2c1, W2b[nd * 8 + 4 + q], y, 0, 0, 0);
    const float bb1 = bias[nd], bb2 = bias[64 + nd];
#pragma unroll
    for (int r = 0; r < 4; ++r) { z[r] += bb1; y[r] += bb2; }

#pragma unroll
    for (int r = 0; r < 4; ++r) {
        sO[q * 4 + r][nd]      = __float2bfloat16(z[r]);
        sO[q * 4 + r][64 + nd] = __float2bfloat16(y[r]);
    }
    __syncthreads();

    s16x8 ga[4];
#pragma unroll
    for (int c = 0; c < 4; ++c)
        ga[c] = *(const s16x8*)&sO[m][c * 32 + q * 8];

    f32x4 g4 = {0.f, 0.f, 0.f, 0.f};
#pragma unroll
    for (int c = 0; c < 4; ++c)
        g4 = __builtin_amdgcn_mfma_f32_16x16x32_bf16(ga[c], Wgb[nd * 16 + c * 4 + q], g4, 0, 0, 0);
    const float bbg = bias[128 + nd];

#pragma unroll
    for (int r = 0; r < 4; ++r) {
        const float g = 1.0f / (1.0f + __expf(-(g4[r] + bbg)));
        const float v = g * z[r] + (1.0f - g) * y[r];
        const size_t node = (size_t)(base + q * 4 + r);
        if (fp32) ((float*)outv)[node * 64 + nd] = v;
        else      ((__hip_bfloat16*)outv)[node * 64 + nd] = __float2bfloat16(v);
    }
}

// ---------------------------------------------------------------------------
extern "C" void kernel_launch(void* const* d_in, const int* in_sizes, int n_in,
                              void* d_out, int out_size, void* d_ws, size_t ws_size,
                              hipStream_t stream)
{
    const void* x  = d_in[0];
    const int*  ei = (const int*)d_in[1];
    unsigned* ws = (unsigned*)d_ws;

    const int use_xb = (ws_size >= WS_NEED_BYTES) ? 1 : 0;   // constant per dataset

    hipMemsetAsync(ws + WS_CUR, 0, NB * sizeof(unsigned), stream);
    prep_kernel<<<NBKT_BLKS + CONV_BLOCKS, 256, 0, stream>>>(
        x, ei, d_in[2], d_in[3], d_in[4], d_in[5], d_in[6], d_in[7], ws, use_xb);
    csr_kernel<<<NB, 256, 0, stream>>>(ws);
    fused_kernel<<<N_NODES / 16, 256, 0, stream>>>(ws, x, d_out, use_xb);
}

// Round 3
// 150.811 us; speedup vs baseline: 1.4329x; 1.1380x over previous
//
#include <hip/hip_runtime.h>
#include <hip/hip_bf16.h>

#define N_NODES 100000
#define E_TOTAL 800000
#define E1      400000    // first min(4,k_max)*N edges -> scale-1 (subset of scale-2)
#define D       64
#define CAP     32        // max degree slots; P(deg>32 | Poisson(8)) ~ 2e-11/node

// ---- bucketed CSR build ----------------------------------------------------
#define NPB        128                            // nodes per bucket
#define NB         ((N_NODES + NPB - 1) / NPB)    // 782 buckets
#define BSTRIDE    (NPB * CAP)                    // 4096 u32: records alias entries span
#define BCAP       1536                           // mean 1024, sigma~32 -> 16 sigma margin
#define EPB        4096                           // edges per bucket-pass block
#define NBKT_BLKS  ((E_TOTAL + EPB - 1) / EPB)    // 196

typedef short s16x8 __attribute__((ext_vector_type(8)));   // 8 bf16 bit patterns
typedef float f32x4 __attribute__((ext_vector_type(4)));
typedef unsigned u32x4 __attribute__((ext_vector_type(4)));

// ws layout (u32 units):
//   cnt[N] | entries[N*CAP] | W1b[2048] | W2b[2048] | Wgb[4096] | bias[192] | cur[800] | Xb[N*32]
#define WS_CNT     0
#define WS_ENTRIES (N_NODES)                        // byte 400000, 16-B aligned
#define WS_W1B     (WS_ENTRIES + N_NODES * CAP)
#define WS_W2B     (WS_W1B + 2048)
#define WS_WGB     (WS_W2B + 2048)
#define WS_BIAS    (WS_WGB + 4096)                  // b1[64] | b2[64] | bg[64] fp32
#define WS_CUR     (WS_BIAS + 192)                  // NB bucket cursors (pad to 800)
#define WS_XB      (WS_CUR + 800)                   // 16-B aligned
#define WS_NEED_BYTES ((size_t)(WS_XB + (size_t)N_NODES * D / 2) * 4)   // ~26 MB

// prep: weights/bias conversion threads after the bucket blocks
#define PREP_CONV_THREADS (2048 + 24)
#define PREP_CONV_BLOCKS  ((PREP_CONV_THREADS + 255) / 256)   // 9

// csr launch: NB bucket blocks + x-conversion blocks
#define R_X          (N_NODES * D / 8)      // 800000 threads, 8 elems each
#define XCONV_BLOCKS (R_X / 256)            // 3125

__device__ __forceinline__ float ldv(const void* p, size_t idx, int fp32)
{
    return fp32 ? ((const float*)p)[idx]
                : __bfloat162float(((const __hip_bfloat16*)p)[idx]);
}

// block-local dtype detection (blockDim.x == 256).
__device__ __forceinline__ void detect2(const int* ei, const unsigned short* xu,
                                        int* s2, int& e64, int& fp32)
{
    if (threadIdx.x == 0) { s2[0] = 0; s2[1] = 0; }
    __syncthreads();
    if (threadIdx.x < 16 && ei[2 * threadIdx.x + 1] != 0) atomicOr(&s2[0], 1);
    { unsigned u = xu[threadIdx.x]; if (((u >> 7) & 0xFF) >= 0x90) atomicOr(&s2[1], 1); }
    __syncthreads();
    e64 = (s2[0] == 0); fp32 = s2[1];
}

// ---------------------------------------------------------------------------
// prep: bucket blocks bin edges into coarse buckets (LDS-aggregated cursors,
// ~150K global atomics, packed records aliasing the entries region). Trailing
// 9 blocks convert weights->bf16 and biases->f32. x conversion moved to the
// csr launch so it overlaps with binning instead of serializing here.
// ---------------------------------------------------------------------------
__global__ __launch_bounds__(256) void prep_kernel(
    const void* __restrict__ xv, const int* __restrict__ ei,
    const void* __restrict__ W1v, const void* __restrict__ b1v,
    const void* __restrict__ W2v, const void* __restrict__ b2v,
    const void* __restrict__ Wgv, const void* __restrict__ bgv,
    unsigned* __restrict__ ws)
{
    __shared__ int s2[2];
    __shared__ unsigned hist[NB];
    __shared__ unsigned bbase[NB];
    int e64, fp32;
    detect2(ei, (const unsigned short*)xv, s2, e64, fp32);

    if (blockIdx.x < NBKT_BLKS) {                 // ---- bucket pass ----
        for (int j = threadIdx.x; j < NB; j += 256) hist[j] = 0;
        __syncthreads();

        const int e0 = blockIdx.x * EPB;
        int srcv[16], tgtv[16];
#pragma unroll
        for (int i = 0; i < 16; ++i) {            // phase 1: all loads in flight
            const int e = e0 + i * 256 + threadIdx.x;
            srcv[i] = -1;
            if (e < E_TOTAL) {
                if (e64) {
                    srcv[i] = (int)((const uint2*)ei)[e].x;
                    tgtv[i] = (int)((const uint2*)ei)[E_TOTAL + e].x;
                } else {
                    srcv[i] = ei[e]; tgtv[i] = ei[E_TOTAL + e];
                }
            }
        }
        unsigned recv[16], br[16];
#pragma unroll
        for (int i = 0; i < 16; ++i) {            // phase 2: LDS rank
            const int e = e0 + i * 256 + threadIdx.x;
            br[i] = 0xFFFFFFFFu;
            if (srcv[i] >= 0) {
                const unsigned b = (unsigned)srcv[i] >> 7;   // bucket (NPB=128)
                const unsigned r = atomicAdd(&hist[b], 1u);  // LDS rank, <= 4095
                recv[i] = (unsigned)tgtv[i]
                        | ((e < E1) ? (1u << 17) : 0u)
                        | (((unsigned)srcv[i] & (NPB - 1)) << 18);
                br[i] = (b << 16) | r;
            }
        }
        __syncthreads();
        for (int j = threadIdx.x; j < NB; j += 256) {
            const unsigned h = hist[j];
            bbase[j] = h ? atomicAdd(ws + WS_CUR + j, h) : 0u;
        }
        __syncthreads();
#pragma unroll
        for (int i = 0; i < 16; ++i) {
            if (br[i] != 0xFFFFFFFFu) {
                const unsigned b = br[i] >> 16, r = br[i] & 0xFFFFu;
                const unsigned pos = bbase[b] + r;
                if (pos < BCAP)
                    ws[WS_ENTRIES + (size_t)b * BSTRIDE + pos] = recv[i];
            }
        }
        return;
    }

    // ---- weights / bias conversion ----
    const int gid = (blockIdx.x - NBKT_BLKS) * 256 + threadIdx.x;
    __hip_bfloat16* W1b = (__hip_bfloat16*)(ws + WS_W1B);
    __hip_bfloat16* W2b = (__hip_bfloat16*)(ws + WS_W2B);
    __hip_bfloat16* Wgb = (__hip_bfloat16*)(ws + WS_WGB);
    float* bias = (float*)(ws + WS_BIAS);

    if (gid < 2048) {                         // weights: 16384 elems, 8/thread
#pragma unroll
        for (int k = 0; k < 8; ++k) {
            const int i = gid * 8 + k;
            if (i < 4096)       W1b[i]        = __float2bfloat16(ldv(W1v, i, fp32));
            else if (i < 8192)  W2b[i - 4096] = __float2bfloat16(ldv(W2v, i - 4096, fp32));
            else                Wgb[i - 8192] = __float2bfloat16(ldv(Wgv, i - 8192, fp32));
        }
    } else if (gid < 2072) {                  // biases: 192 elems
        const int j = gid - 2048;
#pragma unroll
        for (int k = 0; k < 8; ++k) {
            const int i = j * 8 + k;
            if (i < 64)       bias[i] = ldv(b1v, i, fp32);
            else if (i < 128) bias[i] = ldv(b2v, i - 64, fp32);
            else              bias[i] = ldv(bgv, i - 128, fp32);
        }
    }
}

// ---------------------------------------------------------------------------
// csr_kernel: first NB blocks bin each bucket's records per-node in LDS and
// write cnt[] + entries[] coalesced. Remaining 3125 blocks convert x->bf16 Xb
// (streaming, overlaps with the latency-bound binning). Xb is only read by
// fused_kernel, which launches after this one.
// ---------------------------------------------------------------------------
__global__ __launch_bounds__(256) void csr_kernel(
    const void* __restrict__ xv, unsigned* __restrict__ ws, int use_xb)
{
    __shared__ unsigned cnt_l[NPB];
    __shared__ __align__(16) unsigned ent[NPB * CAP];   // 16 KB
    __shared__ int s2[1];

    if (blockIdx.x < NB) {                    // ---- per-bucket binning ----
        const int b  = blockIdx.x;
        const int n0 = b * NPB;
        const int nn = min(NPB, N_NODES - n0);

        if (threadIdx.x < NPB) cnt_l[threadIdx.x] = 0;
        __syncthreads();

        const unsigned C = min(ws[WS_CUR + b], (unsigned)BCAP);
        for (unsigned r = threadIdx.x; r < C; r += 256) {
            const unsigned rec = ws[WS_ENTRIES + (size_t)b * BSTRIDE + r];
            const unsigned sl  = rec >> 18;
            const unsigned p   = atomicAdd(&cnt_l[sl], 1u);
            if (p < CAP)
                ent[sl * CAP + p] = (rec & 0x1FFFFu) | ((rec & (1u << 17)) ? 0x80000000u : 0u);
        }
        __syncthreads();

        const int tot4 = (nn * CAP) / 4;
        u32x4* dst = (u32x4*)(ws + WS_ENTRIES + (size_t)n0 * CAP);
        const u32x4* srcp = (const u32x4*)ent;
        for (int j = threadIdx.x; j < tot4; j += 256) dst[j] = srcp[j];

        if (threadIdx.x < nn) ws[WS_CNT + n0 + threadIdx.x] = cnt_l[threadIdx.x];
        return;
    }

    // ---- x -> bf16 Xb conversion ----
    if (threadIdx.x == 0) s2[0] = 0;
    __syncthreads();
    { unsigned u = ((const unsigned short*)xv)[threadIdx.x];
      if (((u >> 7) & 0xFF) >= 0x90) atomicOr(&s2[0], 1); }
    __syncthreads();
    const int fp32 = s2[0];

    const int gid = (blockIdx.x - NB) * 256 + threadIdx.x;
    if (gid < R_X && use_xb && fp32) {
        __hip_bfloat16* Xb = (__hip_bfloat16*)(ws + WS_XB);
        const f32x4 v0 = ((const f32x4*)xv)[2 * gid];
        const f32x4 v1 = ((const f32x4*)xv)[2 * gid + 1];
        s16x8 o;
#pragma unroll
        for (int j = 0; j < 4; ++j) {
            o[j]     = (short)__bfloat16_as_ushort(__float2bfloat16(v0[j]));
            o[4 + j] = (short)__bfloat16_as_ushort(__float2bfloat16(v1[j]));
        }
        *(s16x8*)(Xb + (size_t)gid * 8) = o;
    }
}

// ---------------------------------------------------------------------------
// fused gather + MFMA epilogue. 256 thr = 4 waves = 16 nodes/block.
// Gather (this round): BRANCH-FREE. Entry clamped to 0 when past degree, load
// always issued (row 0, L1-hot), loaded word zeroed by cndmask -> padded
// slots contribute exactly +0.0. rmax padded to a multiple of 4, unroll 4:
// 16 independent bpermutes + 16 independent loads per body, no exec-mask
// branches between them.
// ---------------------------------------------------------------------------
__global__ __launch_bounds__(256) void fused_kernel(
    const unsigned* __restrict__ ws, const void* __restrict__ xv,
    void* __restrict__ outv, int use_xb)
{
    __shared__ __align__(16) __hip_bfloat16 sS[16][136];  // s1|s2 rows per node
    __shared__ __align__(16) __hip_bfloat16 sO[16][136];  // o1|o2 rows per node
    __shared__ int s2d[2];

    if (threadIdx.x == 0) s2d[0] = 0;
    __syncthreads();
    { unsigned u = ((const unsigned short*)xv)[threadIdx.x];
      if (((u >> 7) & 0xFF) >= 0x90) atomicOr(&s2d[0], 1); }
    __syncthreads();
    const int fp32 = s2d[0];

    const int w    = threadIdx.x >> 6;
    const int lane = threadIdx.x & 63;
    const int base = blockIdx.x * 16;

    const int direct_f32 = (fp32 && !use_xb);     // fallback: no Xb space
    const char* xb = (use_xb && fp32) ? (const char*)(ws + WS_XB) : (const char*)xv;
    const float* xf = (const float*)xv;

    // ---- phase A: concurrent cnt + entry loads for this wave's 4 nodes ----
    unsigned eraw[4], entv[4], degr[4]; int degc[4];
#pragma unroll
    for (int i = 0; i < 4; ++i) {
        const int n = base + w * 4 + i;
        degr[i] = ws[WS_CNT + n];                                  // independent
        eraw[i] = (lane < CAP) ? ws[WS_ENTRIES + (size_t)n * CAP + lane] : 0u;
    }
#pragma unroll
    for (int i = 0; i < 4; ++i) {
        degc[i] = (int)min(degr[i], (unsigned)CAP);
        entv[i] = (lane < degc[i]) ? eraw[i] : 0u;                 // mask garbage
    }

    const int half = lane >> 5;       // which of the 2 rows in a chunk
    const int cc   = lane & 31;       // dim-pair index: dims 2cc, 2cc+1

    if (!direct_f32) {
        int c1[4];
#pragma unroll
        for (int i = 0; i < 4; ++i)
            c1[i] = (int)__popcll(__ballot(entv[i] & 0x80000000u));

        float s1x[4], s1y[4], s2x[4], s2y[4];
#pragma unroll
        for (int i = 0; i < 4; ++i) { s1x[i] = s1y[i] = s2x[i] = s2y[i] = 0.f; }

        int rmax = 0;
#pragma unroll
        for (int i = 0; i < 4; ++i) rmax = max(rmax, (degc[i] + 1) >> 1);
        rmax = (rmax + 3) & ~3;       // pad to unroll factor (extra slots add +0.0)

#pragma unroll 4
        for (int r = 0; r < rmax; ++r) {
#pragma unroll
            for (int i = 0; i < 4; ++i) {
                const int j = 2 * r + half;
                unsigned en = __shfl(entv[i], j);       // ds_bpermute
                en = (j < degc[i]) ? en : 0u;           // clamp: row 0, flag 0
                unsigned u = *(const unsigned*)(xb + ((size_t)(en & 0x7FFFFFFFu) << 7)
                                                   + ((unsigned)cc << 2));
                u = (j < degc[i]) ? u : 0u;             // zero contribution
                const float fx = __uint_as_float(u << 16);          // dim 2cc
                const float fy = __uint_as_float(u & 0xFFFF0000u);  // dim 2cc+1
                const float fl = (en & 0x80000000u) ? 1.f : 0.f;
                s2x[i] += fx; s2y[i] += fy;
                s1x[i] = fmaf(fl, fx, s1x[i]); s1y[i] = fmaf(fl, fy, s1y[i]);
            }
        }

#pragma unroll
        for (int i = 0; i < 4; ++i) {
            const int nl = w * 4 + i;
            float a = s1x[i], b = s1y[i], c = s2x[i], d = s2y[i];
            a += __shfl_xor(a, 32); b += __shfl_xor(b, 32);
            c += __shfl_xor(c, 32); d += __shfl_xor(d, 32);
            const float inv1 = 1.0f / ((float)c1[i] + 1e-6f);
            const float inv2 = 1.0f / ((float)degr[i] + 1e-6f);
            if (lane < 32) {   // lanes 0..31 own dim pairs 0..31
                const __hip_bfloat162 p1 = __float22bfloat162_rn({a * inv1, b * inv1});
                const __hip_bfloat162 p2 = __float22bfloat162_rn({c * inv2, d * inv2});
                *(__hip_bfloat162*)&sS[nl][2 * cc]      = p1;
                *(__hip_bfloat162*)&sS[nl][64 + 2 * cc] = p2;
            }
        }
    } else {
        // fallback: direct fp32 x, scalar per-edge row loads (rare path)
#pragma unroll
        for (int i = 0; i < 4; ++i) {
            const int nl = w * 4 + i;
            const int c1 = (int)__popcll(__ballot(entv[i] & 0x80000000u));
            float s1x = 0.f, s2x = 0.f;
            for (int j = 0; j < degc[i]; ++j) {
                const unsigned en = __builtin_amdgcn_readlane(entv[i], j);
                const float v = xf[(size_t)(en & 0x7FFFFFFFu) * D + lane];
                s2x += v;
                if (en & 0x80000000u) s1x += v;
            }
            const float inv1 = 1.0f / ((float)c1 + 1e-6f);
            const float inv2 = 1.0f / ((float)degr[i] + 1e-6f);
            sS[nl][lane]      = __float2bfloat16(s1x * inv1);
            sS[nl][64 + lane] = __float2bfloat16(s2x * inv2);
        }
    }
    __syncthreads();

    // ---- phase B: MFMA epilogue; wave w computes output dims [16w,16w+16) ----
    const int m = lane & 15;          // A-row carrier / C-col index
    const int q = lane >> 4;          // quad
    const int nd = w * 16 + m;        // output dim this lane computes

    const s16x8* W1b = (const s16x8*)(ws + WS_W1B);
    const s16x8* W2b = (const s16x8*)(ws + WS_W2B);
    const s16x8* Wgb = (const s16x8*)(ws + WS_WGB);
    const float* bias = (const float*)(ws + WS_BIAS);

    const s16x8 a1c0 = *(const s16x8*)&sS[m][q * 8];
    const s16x8 a1c1 = *(const s16x8*)&sS[m][32 + q * 8];
    const s16x8 a2c0 = *(const s16x8*)&sS[m][64 + q * 8];
    const s16x8 a2c1 = *(const s16x8*)&sS[m][96 + q * 8];

    f32x4 z = {0.f, 0.f, 0.f, 0.f};
    z = __builtin_amdgcn_mfma_f32_16x16x32_bf16(a1c0, W1b[nd * 8 + q],     z, 0, 0, 0);
    z = __builtin_amdgcn_mfma_f32_16x16x32_bf16(a1c1, W1b[nd * 8 + 4 + q], z, 0, 0, 0);
    f32x4 y = {0.f, 0.f, 0.f, 0.f};
    y = __builtin_amdgcn_mfma_f32_16x16x32_bf16(a2c0, W2b[nd * 8 + q],     y, 0, 0, 0);
    y = __builtin_amdgcn_mfma_f32_16x16x32_bf16(a2c1, W2b[nd * 8 + 4 + q], y, 0, 0, 0);
    const float bb1 = bias[nd], bb2 = bias[64 + nd];
#pragma unroll
    for (int r = 0; r < 4; ++r) { z[r] += bb1; y[r] += bb2; }

#pragma unroll
    for (int r = 0; r < 4; ++r) {
        sO[q * 4 + r][nd]      = __float2bfloat16(z[r]);
        sO[q * 4 + r][64 + nd] = __float2bfloat16(y[r]);
    }
    __syncthreads();

    s16x8 ga[4];
#pragma unroll
    for (int c = 0; c < 4; ++c)
        ga[c] = *(const s16x8*)&sO[m][c * 32 + q * 8];

    f32x4 g4 = {0.f, 0.f, 0.f, 0.f};
#pragma unroll
    for (int c = 0; c < 4; ++c)
        g4 = __builtin_amdgcn_mfma_f32_16x16x32_bf16(ga[c], Wgb[nd * 16 + c * 4 + q], g4, 0, 0, 0);
    const float bbg = bias[128 + nd];

#pragma unroll
    for (int r = 0; r < 4; ++r) {
        const float g = 1.0f / (1.0f + __expf(-(g4[r] + bbg)));
        const float v = g * z[r] + (1.0f - g) * y[r];
        const size_t node = (size_t)(base + q * 4 + r);
        if (fp32) ((float*)outv)[node * 64 + nd] = v;
        else      ((__hip_bfloat16*)outv)[node * 64 + nd] = __float2bfloat16(v);
    }
}

// ---------------------------------------------------------------------------
extern "C" void kernel_launch(void* const* d_in, const int* in_sizes, int n_in,
                              void* d_out, int out_size, void* d_ws, size_t ws_size,
                              hipStream_t stream)
{
    const void* x  = d_in[0];
    const int*  ei = (const int*)d_in[1];
    unsigned* ws = (unsigned*)d_ws;

    const int use_xb = (ws_size >= WS_NEED_BYTES) ? 1 : 0;   // constant per dataset

    hipMemsetAsync(ws + WS_CUR, 0, 800 * sizeof(unsigned), stream);
    prep_kernel<<<NBKT_BLKS + PREP_CONV_BLOCKS, 256, 0, stream>>>(
        x, ei, d_in[2], d_in[3], d_in[4], d_in[5], d_in[6], d_in[7], ws);
    csr_kernel<<<NB + XCONV_BLOCKS, 256, 0, stream>>>(x, ws, use_xb);
    fused_kernel<<<N_NODES / 16, 256, 0, stream>>>(ws, x, d_out, use_xb);
}